// Round 10
// baseline (1635.997 us; speedup 1.0000x reference)
//
#include <hip/hip_runtime.h>
#include <hip/hip_bf16.h>
#include <math.h>

#define B_ 4
#define S_ 2048
#define D_ 512
#define H_ 8
#define DK_ 64

typedef __bf16 bf16x8 __attribute__((ext_vector_type(8)));
typedef float f32x16 __attribute__((ext_vector_type(16)));
typedef float f32x4 __attribute__((ext_vector_type(4)));

static __device__ __forceinline__ unsigned short f2bf(float f) {
    unsigned int u = __builtin_bit_cast(unsigned int, f);
    unsigned int r = (u + 0x7FFFu + ((u >> 16) & 1u)) >> 16;
    return (unsigned short)r;
}

// ---- x (f32) -> bf16, vectorized ----
__global__ void k_convert_x(const float* __restrict__ x, unsigned short* __restrict__ xb, int n4) {
    int i = blockIdx.x * blockDim.x + threadIdx.x;
    if (i >= n4) return;
    const float4 v = reinterpret_cast<const float4*>(x)[i];
    ushort4 o;
    o.x = f2bf(v.x); o.y = f2bf(v.y); o.z = f2bf(v.z); o.w = f2bf(v.w);
    reinterpret_cast<ushort4*>(xb)[i] = o;
}

// ---- W_Q/W_K [H][D][DK] f32 -> [H][DK][D] bf16 ----
__global__ void k_transpose_w(const float* __restrict__ wq, const float* __restrict__ wk,
                              unsigned short* __restrict__ wqT, unsigned short* __restrict__ wkT) {
    int idx = blockIdx.x * blockDim.x + threadIdx.x;
    const int n = H_ * DK_ * D_;
    const float* src = idx < n ? wq : wk;
    unsigned short* dst = idx < n ? wqT : wkT;
    int o = idx < n ? idx : idx - n;
    int d  = o % D_;
    int hk = o / D_;
    int k  = hk % DK_;
    int h  = hk / DK_;
    dst[o] = f2bf(src[(h * D_ + d) * DK_ + k]);
}

// ---- decay table tab[h][n] = gamma_h^n ----
__global__ void k_decay(float* __restrict__ tab) {
    int i = blockIdx.x * blockDim.x + threadIdx.x;
    if (i >= H_ * S_) return;
    int h = i / S_;
    int n = i % S_;
    double xv = -3.4657359027997265 - (double)h * (2.772588722239781 / 7.0);
    double g = 1.0 - exp(xv);
    tab[i] = (float)pow(g, (double)n);
}

// ---- zero output 0 ----
__global__ void k_zero(float4* __restrict__ p, int n4) {
    int i = blockIdx.x * blockDim.x + threadIdx.x;
    if (i < n4) { float4 z = {0.f, 0.f, 0.f, 0.f}; p[i] = z; }
}

// ---- zero-fill strictly-upper supertiles of A  [INSTRUMENTED x16] ----
__global__ __launch_bounds__(256) void k_fill_upper(float* __restrict__ aout) {
    const int bh = blockIdx.y;
    int r = blockIdx.x;
    int g = 0, cum = 0;
    for (; g < 7; ++g) { int cnt = 4 * (7 - g); if (r < cum + cnt) break; cum += cnt; }
    const int rr  = r - cum;
    const int per = 7 - g;
    const int panel = g * 4 + rr / per;
    const int st    = g + 1 + rr % per;

    float* base = aout + (size_t)bh * S_ * S_ + (size_t)(panel * 64) * S_ + st * 256;
    const int t = threadIdx.x;
    f32x4 z = {0.f, 0.f, 0.f, 0.f};
#pragma unroll 1
    for (int rep = 0; rep < 16; ++rep) {
#pragma unroll
        for (int j = 0; j < 16; ++j) {
            int u = t + j * 256;
            int row = u >> 6;
            int c4  = u & 63;
            *reinterpret_cast<f32x4*>(base + (size_t)row * S_ + c4 * 4) = z;
        }
    }
}

// ---- projection GEMM, fused all heads  [INSTRUMENTED x32] ----
__global__ __launch_bounds__(256) void k_proj(const unsigned short* __restrict__ xb,
                                              const unsigned short* __restrict__ wqT,
                                              const unsigned short* __restrict__ wkT,
                                              unsigned short* __restrict__ qb,
                                              unsigned short* __restrict__ kb) {
    const int lane = threadIdx.x & 63;
    const int wave = threadIdx.x >> 6;
    const int m0 = blockIdx.x * 32;
    const int ncol0 = blockIdx.y * 512 + wave * 128;
    const int row  = lane & 31;
    const int koff = (lane >> 5) * 8;

    const unsigned short* wt = (ncol0 >> 9) ? wkT : wqT;
    unsigned short* outp     = (ncol0 >> 9) ? kb  : qb;

#pragma unroll 1
    for (int rep = 0; rep < 32; ++rep) {
        const unsigned short* aptr = xb + (size_t)(m0 + row) * D_ + koff;
        const unsigned short* bptr0 = wt + (size_t)((ncol0 +  0 + row) & 511) * D_ + koff;
        const unsigned short* bptr1 = wt + (size_t)((ncol0 + 32 + row) & 511) * D_ + koff;
        const unsigned short* bptr2 = wt + (size_t)((ncol0 + 64 + row) & 511) * D_ + koff;
        const unsigned short* bptr3 = wt + (size_t)((ncol0 + 96 + row) & 511) * D_ + koff;

        f32x16 acc0 = {}, acc1 = {}, acc2 = {}, acc3 = {};
        for (int kk = 0; kk < D_; kk += 16) {
            bf16x8 a = *reinterpret_cast<const bf16x8*>(aptr + kk);
            acc0 = __builtin_amdgcn_mfma_f32_32x32x16_bf16(a, *reinterpret_cast<const bf16x8*>(bptr0 + kk), acc0, 0, 0, 0);
            acc1 = __builtin_amdgcn_mfma_f32_32x32x16_bf16(a, *reinterpret_cast<const bf16x8*>(bptr1 + kk), acc1, 0, 0, 0);
            acc2 = __builtin_amdgcn_mfma_f32_32x32x16_bf16(a, *reinterpret_cast<const bf16x8*>(bptr2 + kk), acc2, 0, 0, 0);
            acc3 = __builtin_amdgcn_mfma_f32_32x32x16_bf16(a, *reinterpret_cast<const bf16x8*>(bptr3 + kk), acc3, 0, 0, 0);
        }

        const f32x16* accs[4] = { &acc0, &acc1, &acc2, &acc3 };
#pragma unroll
        for (int nb = 0; nb < 4; ++nb) {
            int n = ncol0 + nb * 32 + (lane & 31);
            int h = (n >> 6) & 7;
            int k = n & 63;
#pragma unroll
            for (int r = 0; r < 16; ++r) {
                int rowD = (r & 3) + 8 * (r >> 2) + 4 * (lane >> 5);
                int m = m0 + rowD;
                int bidx = m >> 11, s = m & 2047;
                outp[(((size_t)bidx * H_ + h) * S_ + s) * DK_ + k] = f2bf((*accs[nb])[r]);
            }
        }
    }
}

// ---- scores, lower-triangle only  [INSTRUMENTED x4] ----
__global__ __launch_bounds__(256) void k_score(const unsigned short* __restrict__ qb,
                                               const unsigned short* __restrict__ kb,
                                               const float* __restrict__ tab,
                                               float* __restrict__ aout) {
    const int lane = threadIdx.x & 63;
    const int w    = threadIdx.x >> 6;
    const int id   = blockIdx.x;
    const int c    = id & 7, sidx = id >> 3;
    const int bh   = (c >> 1) + 4 * (sidx >> 3);
    const int p    = ((sidx & 7) << 1) | (c & 1);
    const int h    = bh & (H_ - 1);
    float* ablk = aout + (size_t)bh * S_ * S_;
    const float* th = tab + h * S_;

    __shared__ float tile[64 * 256];

    const int col  = lane & 31;
    const int hi   = lane >> 5;
    const int koff = hi * 8;

    const float c1 = 1.0f / th[col];
    float grc[16];
    int rowDv[16];
#pragma unroll
    for (int r = 0; r < 16; ++r) {
        rowDv[r] = (r & 3) + 8 * (r >> 2) + 4 * hi;
        grc[r] = th[rowDv[r]] * c1;
    }

#pragma unroll 1
    for (int rep = 0; rep < 4; ++rep) {
    for (int pp = 0; pp < 2; ++pp) {
        const int panel = pp ? (31 - p) : p;
        const int s0 = panel * 64;
        const int qq = panel >> 2;
        const int rb = panel & 3;

        bf16x8 qf[2][4];
#pragma unroll
        for (int rg = 0; rg < 2; ++rg) {
            const unsigned short* qp = qb + ((size_t)bh * S_ + s0 + rg * 32 + col) * DK_ + koff;
#pragma unroll
            for (int i = 0; i < 4; ++i)
                qf[rg][i] = *reinterpret_cast<const bf16x8*>(qp + 16 * i);
        }

        for (int st = 0; st <= qq; ++st) {
            const int t0 = st * 256;
            const int ct0 = t0 + w * 64;
            const bool active = (st < qq) || (w <= rb);
            if (active) {
                f32x16 acc[2][2] = {{{}, {}}, {{}, {}}};
#pragma unroll
                for (int cg = 0; cg < 2; ++cg) {
                    const unsigned short* kp = kb + ((size_t)bh * S_ + ct0 + cg * 32 + col) * DK_ + koff;
                    bf16x8 kf0 = *reinterpret_cast<const bf16x8*>(kp);
                    bf16x8 kf1 = *reinterpret_cast<const bf16x8*>(kp + 16);
                    bf16x8 kf2 = *reinterpret_cast<const bf16x8*>(kp + 32);
                    bf16x8 kf3 = *reinterpret_cast<const bf16x8*>(kp + 48);
#pragma unroll
                    for (int rg = 0; rg < 2; ++rg) {
                        acc[rg][cg] = __builtin_amdgcn_mfma_f32_32x32x16_bf16(qf[rg][0], kf0, acc[rg][cg], 0, 0, 0);
                        acc[rg][cg] = __builtin_amdgcn_mfma_f32_32x32x16_bf16(qf[rg][1], kf1, acc[rg][cg], 0, 0, 0);
                        acc[rg][cg] = __builtin_amdgcn_mfma_f32_32x32x16_bf16(qf[rg][2], kf2, acc[rg][cg], 0, 0, 0);
                        acc[rg][cg] = __builtin_amdgcn_mfma_f32_32x32x16_bf16(qf[rg][3], kf3, acc[rg][cg], 0, 0, 0);
                    }
                }
                if (st < qq || w < rb) {
#pragma unroll
                    for (int rg = 0; rg < 2; ++rg) {
#pragma unroll
                        for (int cg = 0; cg < 2; ++cg) {
                            const float sc = th[s0 + rg * 32 - ct0 - cg * 32];
#pragma unroll
                            for (int r = 0; r < 16; ++r)
                                tile[(rg * 32 + rowDv[r]) * 256 + w * 64 + cg * 32 + col] =
                                    acc[rg][cg][r] * grc[r] * sc;
                        }
                    }
                } else {
#pragma unroll
                    for (int rg = 0; rg < 2; ++rg) {
#pragma unroll
                        for (int cg = 0; cg < 2; ++cg) {
                            const int dbase = 32 * (rg - cg);
#pragma unroll
                            for (int r = 0; r < 16; ++r) {
                                int d = dbase + rowDv[r] - col;
                                float v = (d >= 0) ? acc[rg][cg][r] * th[d] : 0.0f;
                                tile[(rg * 32 + rowDv[r]) * 256 + w * 64 + cg * 32 + col] = v;
                            }
                        }
                    }
                }
            } else {
                f32x4 z = {0.f, 0.f, 0.f, 0.f};
#pragma unroll
                for (int i = 0; i < 16; ++i) {
                    int r = i * 4 + (lane >> 4);
                    int cc = (lane & 15) * 4;
                    *reinterpret_cast<f32x4*>(&tile[r * 256 + w * 64 + cc]) = z;
                }
            }
            __syncthreads();
#pragma unroll
            for (int r = 0; r < 16; ++r) {
                int row = w * 16 + r;
                f32x4 v = *reinterpret_cast<const f32x4*>(&tile[row * 256 + lane * 4]);
                *reinterpret_cast<f32x4*>(ablk + (size_t)(s0 + row) * S_ + t0 + lane * 4) = v;
            }
            __syncthreads();
        }
    }
    }  // rep
}

extern "C" void kernel_launch(void* const* d_in, const int* in_sizes, int n_in,
                              void* d_out, int out_size, void* d_ws, size_t ws_size,
                              hipStream_t stream) {
    const float* x  = (const float*)d_in[0];
    const float* wq = (const float*)d_in[1];
    const float* wk = (const float*)d_in[2];

    char* ws = (char*)d_ws;
    unsigned short* xb  = (unsigned short*)(ws);               //  8,388,608 B
    unsigned short* wqT = (unsigned short*)(ws + 8388608);     //    524,288 B
    unsigned short* wkT = (unsigned short*)(ws + 8912896);     //    524,288 B
    unsigned short* qb  = (unsigned short*)(ws + 9437184);     //  8,388,608 B
    unsigned short* kb  = (unsigned short*)(ws + 17825792);    //  8,388,608 B
    float*          tab = (float*)(ws + 26214400);             //     65,536 B

    float* out0 = (float*)d_out;
    float* aout = (float*)d_out + (size_t)B_ * S_ * D_;

    hipLaunchKernelGGL(k_zero, dim3((B_*S_*D_/4 + 255)/256), dim3(256), 0, stream,
                       (float4*)out0, B_*S_*D_/4);
    hipLaunchKernelGGL(k_fill_upper, dim3(112, 32), dim3(256), 0, stream, aout);
    hipLaunchKernelGGL(k_convert_x, dim3((B_*S_*D_/4 + 255)/256), dim3(256), 0, stream,
                       x, xb, B_*S_*D_/4);
    hipLaunchKernelGGL(k_transpose_w, dim3((2*H_*DK_*D_ + 255)/256), dim3(256), 0, stream,
                       wq, wk, wqT, wkT);
    hipLaunchKernelGGL(k_decay, dim3((H_*S_ + 255)/256), dim3(256), 0, stream, tab);
    hipLaunchKernelGGL(k_proj, dim3(B_*S_/32, 2), dim3(256), 0, stream,
                       xb, wqT, wkT, qb, kb);
    hipLaunchKernelGGL(k_score, dim3(512), dim3(256), 0, stream,
                       qb, kb, tab, aout);
}

// Round 11
// 180.862 us; speedup vs baseline: 9.0456x; 9.0456x over previous
//
#include <hip/hip_runtime.h>
#include <hip/hip_bf16.h>
#include <math.h>

#define B_ 4
#define S_ 2048
#define D_ 512
#define H_ 8
#define DK_ 64

typedef __bf16 bf16x8 __attribute__((ext_vector_type(8)));
typedef float f32x16 __attribute__((ext_vector_type(16)));
typedef float f32x4 __attribute__((ext_vector_type(4)));

static __device__ __forceinline__ unsigned short f2bf(float f) {
    unsigned int u = __builtin_bit_cast(unsigned int, f);
    unsigned int r = (u + 0x7FFFu + ((u >> 16) & 1u)) >> 16;
    return (unsigned short)r;
}

// ---- W_Q/W_K [H][D][DK] f32 -> [H][DK][D] bf16 ----
__global__ void k_transpose_w(const float* __restrict__ wq, const float* __restrict__ wk,
                              unsigned short* __restrict__ wqT, unsigned short* __restrict__ wkT) {
    int idx = blockIdx.x * blockDim.x + threadIdx.x;
    const int n = H_ * DK_ * D_;
    const float* src = idx < n ? wq : wk;
    unsigned short* dst = idx < n ? wqT : wkT;
    int o = idx < n ? idx : idx - n;
    int d  = o % D_;
    int hk = o / D_;
    int k  = hk % DK_;
    int h  = hk / DK_;
    dst[o] = f2bf(src[(h * D_ + d) * DK_ + k]);
}

// ---- decay table tab[h][n] = gamma_h^n ----
__global__ void k_decay(float* __restrict__ tab) {
    int i = blockIdx.x * blockDim.x + threadIdx.x;
    if (i >= H_ * S_) return;
    int h = i / S_;
    int n = i % S_;
    double xv = -3.4657359027997265 - (double)h * (2.772588722239781 / 7.0);
    double g = 1.0 - exp(xv);
    tab[i] = (float)pow(g, (double)n);
}

// ---- merged zero-fill: out0 (16.8MB) + strictly-upper supertiles of A (224MB) ----
// grid (116, 32): x<112 -> one 64x256 upper supertile of bh; x>=112 -> out0 chunk.
__global__ __launch_bounds__(256) void k_fill_all(float* __restrict__ aout, float* __restrict__ out0) {
    const int bh = blockIdx.y;
    f32x4 z = {0.f, 0.f, 0.f, 0.f};
    if (blockIdx.x >= 112) {
        // out0: 1,048,576 f32x4 over 128 (chunk) x 256 (thread) x 32 (j)
        const int chunk = (blockIdx.x - 112) + 4 * bh;
        f32x4* base = reinterpret_cast<f32x4*>(out0) + (size_t)chunk * 8192;
#pragma unroll
        for (int j = 0; j < 32; ++j)
            base[threadIdx.x + j * 256] = z;
        return;
    }
    int r = blockIdx.x;
    int g = 0, cum = 0;
    for (; g < 7; ++g) { int cnt = 4 * (7 - g); if (r < cum + cnt) break; cum += cnt; }
    const int rr  = r - cum;
    const int per = 7 - g;
    const int panel = g * 4 + rr / per;
    const int st    = g + 1 + rr % per;

    float* base = aout + (size_t)bh * S_ * S_ + (size_t)(panel * 64) * S_ + st * 256;
    const int t = threadIdx.x;
#pragma unroll
    for (int j = 0; j < 16; ++j) {
        int u = t + j * 256;
        int row = u >> 6;
        int c4  = u & 63;
        *reinterpret_cast<f32x4*>(base + (size_t)row * S_ + c4 * 4) = z;
    }
}

// ---- projection GEMM v2: A-tile in LDS (shared by 4 waves), convert fused ----
// grid (256 m-blocks, 2 halves {Q,K}), block 256 = 4 waves.
// Block: 32 rows x 512 cols of one half. Stage x-tile f32->bf16 into LDS once;
// per K-step each wave: 1 ds_read + 4 global B loads (1MB set, L2-resident)
// : 4 MFMAs, K fully unrolled for deep load pipelining.
__global__ __launch_bounds__(256, 2) void k_proj(const float* __restrict__ x,
                                                 const unsigned short* __restrict__ wqT,
                                                 const unsigned short* __restrict__ wkT,
                                                 unsigned short* __restrict__ qb,
                                                 unsigned short* __restrict__ kb) {
    const int tid  = threadIdx.x;
    const int lane = tid & 63;
    const int wave = tid >> 6;
    const int m0   = blockIdx.x * 32;
    const int half = blockIdx.y;
    const unsigned short* wt = half ? wkT : wqT;
    unsigned short* outp     = half ? kb  : qb;

    __shared__ unsigned short atile[32 * 520];   // stride 520 bf16 (16B-aligned rows, 4-way max)

    // stage A: 4096 float4 chunks; thread t does chunks t+i*256 (coalesced 1KB/instr)
    {
        const float4* xsrc = reinterpret_cast<const float4*>(x + (size_t)m0 * D_);
#pragma unroll
        for (int i = 0; i < 16; ++i) {
            int u   = tid + i * 256;
            int row = u >> 7, c4 = u & 127;
            float4 v = xsrc[u];
            ushort4 o;
            o.x = f2bf(v.x); o.y = f2bf(v.y); o.z = f2bf(v.z); o.w = f2bf(v.w);
            *reinterpret_cast<ushort4*>(&atile[row * 520 + c4 * 4]) = o;
        }
    }
    __syncthreads();

    const int row  = lane & 31;
    const int col  = lane & 31;
    const int hi   = lane >> 5;
    const int koff = hi * 8;
    const int n0   = wave * 128;                 // col offset within the half

    const unsigned short* b0 = wt + (size_t)(n0 +  0 + row) * D_ + koff;
    const unsigned short* b1 = wt + (size_t)(n0 + 32 + row) * D_ + koff;
    const unsigned short* b2 = wt + (size_t)(n0 + 64 + row) * D_ + koff;
    const unsigned short* b3 = wt + (size_t)(n0 + 96 + row) * D_ + koff;
    const unsigned short* ap = atile + row * 520 + koff;

    f32x16 acc0 = {}, acc1 = {}, acc2 = {}, acc3 = {};
#pragma unroll
    for (int kk = 0; kk < D_; kk += 16) {
        bf16x8 a = *reinterpret_cast<const bf16x8*>(ap + kk);
        acc0 = __builtin_amdgcn_mfma_f32_32x32x16_bf16(a, *reinterpret_cast<const bf16x8*>(b0 + kk), acc0, 0, 0, 0);
        acc1 = __builtin_amdgcn_mfma_f32_32x32x16_bf16(a, *reinterpret_cast<const bf16x8*>(b1 + kk), acc1, 0, 0, 0);
        acc2 = __builtin_amdgcn_mfma_f32_32x32x16_bf16(a, *reinterpret_cast<const bf16x8*>(b2 + kk), acc2, 0, 0, 0);
        acc3 = __builtin_amdgcn_mfma_f32_32x32x16_bf16(a, *reinterpret_cast<const bf16x8*>(b3 + kk), acc3, 0, 0, 0);
    }

#define EPI(ACC, NB) { \
    int n = n0 + (NB) * 32 + col; \
    int hh = n >> 6, k = n & 63; \
    _Pragma("unroll") \
    for (int r = 0; r < 16; ++r) { \
        int rowD = (r & 3) + 8 * (r >> 2) + 4 * hi; \
        int m = m0 + rowD; \
        int bidx = m >> 11, s = m & 2047; \
        outp[(((size_t)bidx * H_ + hh) * S_ + s) * DK_ + k] = f2bf(ACC[r]); \
    } }
    EPI(acc0, 0) EPI(acc1, 1) EPI(acc2, 2) EPI(acc3, 3)
#undef EPI
}

// ---- scores, lower-triangle only (unchanged from round 9) ----
__global__ __launch_bounds__(256) void k_score(const unsigned short* __restrict__ qb,
                                               const unsigned short* __restrict__ kb,
                                               const float* __restrict__ tab,
                                               float* __restrict__ aout) {
    const int lane = threadIdx.x & 63;
    const int w    = threadIdx.x >> 6;
    const int id   = blockIdx.x;
    const int c    = id & 7, sidx = id >> 3;
    const int bh   = (c >> 1) + 4 * (sidx >> 3);
    const int p    = ((sidx & 7) << 1) | (c & 1);
    const int h    = bh & (H_ - 1);
    float* ablk = aout + (size_t)bh * S_ * S_;
    const float* th = tab + h * S_;

    __shared__ float tile[64 * 256];

    const int col  = lane & 31;
    const int hi   = lane >> 5;
    const int koff = hi * 8;

    const float c1 = 1.0f / th[col];
    float grc[16];
    int rowDv[16];
#pragma unroll
    for (int r = 0; r < 16; ++r) {
        rowDv[r] = (r & 3) + 8 * (r >> 2) + 4 * hi;
        grc[r] = th[rowDv[r]] * c1;
    }

    for (int pp = 0; pp < 2; ++pp) {
        const int panel = pp ? (31 - p) : p;
        const int s0 = panel * 64;
        const int qq = panel >> 2;
        const int rb = panel & 3;

        bf16x8 qf[2][4];
#pragma unroll
        for (int rg = 0; rg < 2; ++rg) {
            const unsigned short* qp = qb + ((size_t)bh * S_ + s0 + rg * 32 + col) * DK_ + koff;
#pragma unroll
            for (int i = 0; i < 4; ++i)
                qf[rg][i] = *reinterpret_cast<const bf16x8*>(qp + 16 * i);
        }

        for (int st = 0; st <= qq; ++st) {
            const int t0 = st * 256;
            const int ct0 = t0 + w * 64;
            const bool active = (st < qq) || (w <= rb);
            if (active) {
                f32x16 acc[2][2] = {{{}, {}}, {{}, {}}};
#pragma unroll
                for (int cg = 0; cg < 2; ++cg) {
                    const unsigned short* kp = kb + ((size_t)bh * S_ + ct0 + cg * 32 + col) * DK_ + koff;
                    bf16x8 kf0 = *reinterpret_cast<const bf16x8*>(kp);
                    bf16x8 kf1 = *reinterpret_cast<const bf16x8*>(kp + 16);
                    bf16x8 kf2 = *reinterpret_cast<const bf16x8*>(kp + 32);
                    bf16x8 kf3 = *reinterpret_cast<const bf16x8*>(kp + 48);
#pragma unroll
                    for (int rg = 0; rg < 2; ++rg) {
                        acc[rg][cg] = __builtin_amdgcn_mfma_f32_32x32x16_bf16(qf[rg][0], kf0, acc[rg][cg], 0, 0, 0);
                        acc[rg][cg] = __builtin_amdgcn_mfma_f32_32x32x16_bf16(qf[rg][1], kf1, acc[rg][cg], 0, 0, 0);
                        acc[rg][cg] = __builtin_amdgcn_mfma_f32_32x32x16_bf16(qf[rg][2], kf2, acc[rg][cg], 0, 0, 0);
                        acc[rg][cg] = __builtin_amdgcn_mfma_f32_32x32x16_bf16(qf[rg][3], kf3, acc[rg][cg], 0, 0, 0);
                    }
                }
                if (st < qq || w < rb) {
#pragma unroll
                    for (int rg = 0; rg < 2; ++rg) {
#pragma unroll
                        for (int cg = 0; cg < 2; ++cg) {
                            const float sc = th[s0 + rg * 32 - ct0 - cg * 32];
#pragma unroll
                            for (int r = 0; r < 16; ++r)
                                tile[(rg * 32 + rowDv[r]) * 256 + w * 64 + cg * 32 + col] =
                                    acc[rg][cg][r] * grc[r] * sc;
                        }
                    }
                } else {
#pragma unroll
                    for (int rg = 0; rg < 2; ++rg) {
#pragma unroll
                        for (int cg = 0; cg < 2; ++cg) {
                            const int dbase = 32 * (rg - cg);
#pragma unroll
                            for (int r = 0; r < 16; ++r) {
                                int d = dbase + rowDv[r] - col;
                                float v = (d >= 0) ? acc[rg][cg][r] * th[d] : 0.0f;
                                tile[(rg * 32 + rowDv[r]) * 256 + w * 64 + cg * 32 + col] = v;
                            }
                        }
                    }
                }
            } else {
                f32x4 z = {0.f, 0.f, 0.f, 0.f};
#pragma unroll
                for (int i = 0; i < 16; ++i) {
                    int r = i * 4 + (lane >> 4);
                    int cc = (lane & 15) * 4;
                    *reinterpret_cast<f32x4*>(&tile[r * 256 + w * 64 + cc]) = z;
                }
            }
            __syncthreads();
#pragma unroll
            for (int r = 0; r < 16; ++r) {
                int row = w * 16 + r;
                f32x4 v = *reinterpret_cast<const f32x4*>(&tile[row * 256 + lane * 4]);
                *reinterpret_cast<f32x4*>(ablk + (size_t)(s0 + row) * S_ + t0 + lane * 4) = v;
            }
            __syncthreads();
        }
    }
}

extern "C" void kernel_launch(void* const* d_in, const int* in_sizes, int n_in,
                              void* d_out, int out_size, void* d_ws, size_t ws_size,
                              hipStream_t stream) {
    const float* x  = (const float*)d_in[0];
    const float* wq = (const float*)d_in[1];
    const float* wk = (const float*)d_in[2];

    char* ws = (char*)d_ws;
    unsigned short* wqT = (unsigned short*)(ws);               //    524,288 B
    unsigned short* wkT = (unsigned short*)(ws + 524288);      //    524,288 B
    unsigned short* qb  = (unsigned short*)(ws + 1048576);     //  8,388,608 B
    unsigned short* kb  = (unsigned short*)(ws + 9437184);     //  8,388,608 B
    float*          tab = (float*)(ws + 17825792);             //     65,536 B

    float* out0 = (float*)d_out;
    float* aout = (float*)d_out + (size_t)B_ * S_ * D_;

    hipLaunchKernelGGL(k_transpose_w, dim3((2*H_*DK_*D_ + 255)/256), dim3(256), 0, stream,
                       wq, wk, wqT, wkT);
    hipLaunchKernelGGL(k_decay, dim3((H_*S_ + 255)/256), dim3(256), 0, stream, tab);
    hipLaunchKernelGGL(k_fill_all, dim3(116, 32), dim3(256), 0, stream, aout, out0);
    hipLaunchKernelGGL(k_proj, dim3(B_*S_/32, 2), dim3(256), 0, stream,
                       x, wqT, wkT, qb, kb);
    hipLaunchKernelGGL(k_score, dim3(512), dim3(256), 0, stream,
                       qb, kb, tab, aout);
}

// Round 12
// 177.480 us; speedup vs baseline: 9.2179x; 1.0191x over previous
//
#include <hip/hip_runtime.h>
#include <hip/hip_bf16.h>
#include <math.h>

#define B_ 4
#define S_ 2048
#define D_ 512
#define H_ 8
#define DK_ 64

typedef __bf16 bf16x8 __attribute__((ext_vector_type(8)));
typedef float f32x16 __attribute__((ext_vector_type(16)));
typedef float f32x4 __attribute__((ext_vector_type(4)));

static __device__ __forceinline__ unsigned short f2bf(float f) {
    unsigned int u = __builtin_bit_cast(unsigned int, f);
    unsigned int r = (u + 0x7FFFu + ((u >> 16) & 1u)) >> 16;
    return (unsigned short)r;
}

// ---- W_Q/W_K [H][D][DK] f32 -> [H][DK][D] bf16 ----
__global__ void k_transpose_w(const float* __restrict__ wq, const float* __restrict__ wk,
                              unsigned short* __restrict__ wqT, unsigned short* __restrict__ wkT) {
    int idx = blockIdx.x * blockDim.x + threadIdx.x;
    const int n = H_ * DK_ * D_;
    const float* src = idx < n ? wq : wk;
    unsigned short* dst = idx < n ? wqT : wkT;
    int o = idx < n ? idx : idx - n;
    int d  = o % D_;
    int hk = o / D_;
    int k  = hk % DK_;
    int h  = hk / DK_;
    dst[o] = f2bf(src[(h * D_ + d) * DK_ + k]);
}

// ---- decay table tab[h][n] = gamma_h^n ----
__global__ void k_decay(float* __restrict__ tab) {
    int i = blockIdx.x * blockDim.x + threadIdx.x;
    if (i >= H_ * S_) return;
    int h = i / S_;
    int n = i % S_;
    double xv = -3.4657359027997265 - (double)h * (2.772588722239781 / 7.0);
    double g = 1.0 - exp(xv);
    tab[i] = (float)pow(g, (double)n);
}

// ---- merged zero-fill: out0 (16.8MB) + strictly-upper supertiles of A (224MB) ----
// grid (116, 32): x<112 -> one 64x256 upper supertile of bh; x>=112 -> out0 chunk.
__global__ __launch_bounds__(256) void k_fill_all(float* __restrict__ aout, float* __restrict__ out0) {
    const int bh = blockIdx.y;
    f32x4 z = {0.f, 0.f, 0.f, 0.f};
    if (blockIdx.x >= 112) {
        // out0: 1,048,576 f32x4 over 128 (chunk) x 256 (thread) x 32 (j)
        const int chunk = (blockIdx.x - 112) + 4 * bh;
        f32x4* base = reinterpret_cast<f32x4*>(out0) + (size_t)chunk * 8192;
#pragma unroll
        for (int j = 0; j < 32; ++j)
            base[threadIdx.x + j * 256] = z;
        return;
    }
    int r = blockIdx.x;
    int g = 0, cum = 0;
    for (; g < 7; ++g) { int cnt = 4 * (7 - g); if (r < cum + cnt) break; cum += cnt; }
    const int rr  = r - cum;
    const int per = 7 - g;
    const int panel = g * 4 + rr / per;
    const int st    = g + 1 + rr % per;

    float* base = aout + (size_t)bh * S_ * S_ + (size_t)(panel * 64) * S_ + st * 256;
    const int t = threadIdx.x;
#pragma unroll
    for (int j = 0; j < 16; ++j) {
        int u = t + j * 256;
        int row = u >> 6;
        int c4  = u & 63;
        *reinterpret_cast<f32x4*>(base + (size_t)row * S_ + c4 * 4) = z;
    }
}

// ---- projection GEMM v2: A-tile in LDS (shared by 4 waves), convert fused ----
// grid (256 m-blocks, 2 halves {Q,K}), block 256 = 4 waves.
// Block: 32 rows x 512 cols of one half. Stage x-tile f32->bf16 into LDS once;
// per K-step each wave: 1 ds_read + 4 global B loads (1MB set, L2-resident)
// : 4 MFMAs, K fully unrolled for deep load pipelining.
__global__ __launch_bounds__(256, 2) void k_proj(const float* __restrict__ x,
                                                 const unsigned short* __restrict__ wqT,
                                                 const unsigned short* __restrict__ wkT,
                                                 unsigned short* __restrict__ qb,
                                                 unsigned short* __restrict__ kb) {
    const int tid  = threadIdx.x;
    const int lane = tid & 63;
    const int wave = tid >> 6;
    const int m0   = blockIdx.x * 32;
    const int half = blockIdx.y;
    const unsigned short* wt = half ? wkT : wqT;
    unsigned short* outp     = half ? kb  : qb;

    __shared__ unsigned short atile[32 * 520];   // stride 520 bf16 (16B-aligned rows, 4-way max)

    // stage A: 4096 float4 chunks; thread t does chunks t+i*256 (coalesced 1KB/instr)
    {
        const float4* xsrc = reinterpret_cast<const float4*>(x + (size_t)m0 * D_);
#pragma unroll
        for (int i = 0; i < 16; ++i) {
            int u   = tid + i * 256;
            int row = u >> 7, c4 = u & 127;
            float4 v = xsrc[u];
            ushort4 o;
            o.x = f2bf(v.x); o.y = f2bf(v.y); o.z = f2bf(v.z); o.w = f2bf(v.w);
            *reinterpret_cast<ushort4*>(&atile[row * 520 + c4 * 4]) = o;
        }
    }
    __syncthreads();

    const int row  = lane & 31;
    const int col  = lane & 31;
    const int hi   = lane >> 5;
    const int koff = hi * 8;
    const int n0   = wave * 128;                 // col offset within the half

    const unsigned short* b0 = wt + (size_t)(n0 +  0 + row) * D_ + koff;
    const unsigned short* b1 = wt + (size_t)(n0 + 32 + row) * D_ + koff;
    const unsigned short* b2 = wt + (size_t)(n0 + 64 + row) * D_ + koff;
    const unsigned short* b3 = wt + (size_t)(n0 + 96 + row) * D_ + koff;
    const unsigned short* ap = atile + row * 520 + koff;

    f32x16 acc0 = {}, acc1 = {}, acc2 = {}, acc3 = {};
#pragma unroll
    for (int kk = 0; kk < D_; kk += 16) {
        bf16x8 a = *reinterpret_cast<const bf16x8*>(ap + kk);
        acc0 = __builtin_amdgcn_mfma_f32_32x32x16_bf16(a, *reinterpret_cast<const bf16x8*>(b0 + kk), acc0, 0, 0, 0);
        acc1 = __builtin_amdgcn_mfma_f32_32x32x16_bf16(a, *reinterpret_cast<const bf16x8*>(b1 + kk), acc1, 0, 0, 0);
        acc2 = __builtin_amdgcn_mfma_f32_32x32x16_bf16(a, *reinterpret_cast<const bf16x8*>(b2 + kk), acc2, 0, 0, 0);
        acc3 = __builtin_amdgcn_mfma_f32_32x32x16_bf16(a, *reinterpret_cast<const bf16x8*>(b3 + kk), acc3, 0, 0, 0);
    }

#define EPI(ACC, NB) { \
    int n = n0 + (NB) * 32 + col; \
    int hh = n >> 6, k = n & 63; \
    _Pragma("unroll") \
    for (int r = 0; r < 16; ++r) { \
        int rowD = (r & 3) + 8 * (r >> 2) + 4 * hi; \
        int m = m0 + rowD; \
        int bidx = m >> 11, s = m & 2047; \
        outp[(((size_t)bidx * H_ + hh) * S_ + s) * DK_ + k] = f2bf(ACC[r]); \
    } }
    EPI(acc0, 0) EPI(acc1, 1) EPI(acc2, 2) EPI(acc3, 3)
#undef EPI
}

// ---- scores, lower-triangle only (unchanged from round 9) ----
__global__ __launch_bounds__(256) void k_score(const unsigned short* __restrict__ qb,
                                               const unsigned short* __restrict__ kb,
                                               const float* __restrict__ tab,
                                               float* __restrict__ aout) {
    const int lane = threadIdx.x & 63;
    const int w    = threadIdx.x >> 6;
    const int id   = blockIdx.x;
    const int c    = id & 7, sidx = id >> 3;
    const int bh   = (c >> 1) + 4 * (sidx >> 3);
    const int p    = ((sidx & 7) << 1) | (c & 1);
    const int h    = bh & (H_ - 1);
    float* ablk = aout + (size_t)bh * S_ * S_;
    const float* th = tab + h * S_;

    __shared__ float tile[64 * 256];

    const int col  = lane & 31;
    const int hi   = lane >> 5;
    const int koff = hi * 8;

    const float c1 = 1.0f / th[col];
    float grc[16];
    int rowDv[16];
#pragma unroll
    for (int r = 0; r < 16; ++r) {
        rowDv[r] = (r & 3) + 8 * (r >> 2) + 4 * hi;
        grc[r] = th[rowDv[r]] * c1;
    }

    for (int pp = 0; pp < 2; ++pp) {
        const int panel = pp ? (31 - p) : p;
        const int s0 = panel * 64;
        const int qq = panel >> 2;
        const int rb = panel & 3;

        bf16x8 qf[2][4];
#pragma unroll
        for (int rg = 0; rg < 2; ++rg) {
            const unsigned short* qp = qb + ((size_t)bh * S_ + s0 + rg * 32 + col) * DK_ + koff;
#pragma unroll
            for (int i = 0; i < 4; ++i)
                qf[rg][i] = *reinterpret_cast<const bf16x8*>(qp + 16 * i);
        }

        for (int st = 0; st <= qq; ++st) {
            const int t0 = st * 256;
            const int ct0 = t0 + w * 64;
            const bool active = (st < qq) || (w <= rb);
            if (active) {
                f32x16 acc[2][2] = {{{}, {}}, {{}, {}}};
#pragma unroll
                for (int cg = 0; cg < 2; ++cg) {
                    const unsigned short* kp = kb + ((size_t)bh * S_ + ct0 + cg * 32 + col) * DK_ + koff;
                    bf16x8 kf0 = *reinterpret_cast<const bf16x8*>(kp);
                    bf16x8 kf1 = *reinterpret_cast<const bf16x8*>(kp + 16);
                    bf16x8 kf2 = *reinterpret_cast<const bf16x8*>(kp + 32);
                    bf16x8 kf3 = *reinterpret_cast<const bf16x8*>(kp + 48);
#pragma unroll
                    for (int rg = 0; rg < 2; ++rg) {
                        acc[rg][cg] = __builtin_amdgcn_mfma_f32_32x32x16_bf16(qf[rg][0], kf0, acc[rg][cg], 0, 0, 0);
                        acc[rg][cg] = __builtin_amdgcn_mfma_f32_32x32x16_bf16(qf[rg][1], kf1, acc[rg][cg], 0, 0, 0);
                        acc[rg][cg] = __builtin_amdgcn_mfma_f32_32x32x16_bf16(qf[rg][2], kf2, acc[rg][cg], 0, 0, 0);
                        acc[rg][cg] = __builtin_amdgcn_mfma_f32_32x32x16_bf16(qf[rg][3], kf3, acc[rg][cg], 0, 0, 0);
                    }
                }
                if (st < qq || w < rb) {
#pragma unroll
                    for (int rg = 0; rg < 2; ++rg) {
#pragma unroll
                        for (int cg = 0; cg < 2; ++cg) {
                            const float sc = th[s0 + rg * 32 - ct0 - cg * 32];
#pragma unroll
                            for (int r = 0; r < 16; ++r)
                                tile[(rg * 32 + rowDv[r]) * 256 + w * 64 + cg * 32 + col] =
                                    acc[rg][cg][r] * grc[r] * sc;
                        }
                    }
                } else {
#pragma unroll
                    for (int rg = 0; rg < 2; ++rg) {
#pragma unroll
                        for (int cg = 0; cg < 2; ++cg) {
                            const int dbase = 32 * (rg - cg);
#pragma unroll
                            for (int r = 0; r < 16; ++r) {
                                int d = dbase + rowDv[r] - col;
                                float v = (d >= 0) ? acc[rg][cg][r] * th[d] : 0.0f;
                                tile[(rg * 32 + rowDv[r]) * 256 + w * 64 + cg * 32 + col] = v;
                            }
                        }
                    }
                }
            } else {
                f32x4 z = {0.f, 0.f, 0.f, 0.f};
#pragma unroll
                for (int i = 0; i < 16; ++i) {
                    int r = i * 4 + (lane >> 4);
                    int cc = (lane & 15) * 4;
                    *reinterpret_cast<f32x4*>(&tile[r * 256 + w * 64 + cc]) = z;
                }
            }
            __syncthreads();
#pragma unroll
            for (int r = 0; r < 16; ++r) {
                int row = w * 16 + r;
                f32x4 v = *reinterpret_cast<const f32x4*>(&tile[row * 256 + lane * 4]);
                *reinterpret_cast<f32x4*>(ablk + (size_t)(s0 + row) * S_ + t0 + lane * 4) = v;
            }
            __syncthreads();
        }
    }
}

extern "C" void kernel_launch(void* const* d_in, const int* in_sizes, int n_in,
                              void* d_out, int out_size, void* d_ws, size_t ws_size,
                              hipStream_t stream) {
    const float* x  = (const float*)d_in[0];
    const float* wq = (const float*)d_in[1];
    const float* wk = (const float*)d_in[2];

    char* ws = (char*)d_ws;
    unsigned short* wqT = (unsigned short*)(ws);               //    524,288 B
    unsigned short* wkT = (unsigned short*)(ws + 524288);      //    524,288 B
    unsigned short* qb  = (unsigned short*)(ws + 1048576);     //  8,388,608 B
    unsigned short* kb  = (unsigned short*)(ws + 9437184);     //  8,388,608 B
    float*          tab = (float*)(ws + 17825792);             //     65,536 B

    float* out0 = (float*)d_out;
    float* aout = (float*)d_out + (size_t)B_ * S_ * D_;

    hipLaunchKernelGGL(k_transpose_w, dim3((2*H_*DK_*D_ + 255)/256), dim3(256), 0, stream,
                       wq, wk, wqT, wkT);
    hipLaunchKernelGGL(k_decay, dim3((H_*S_ + 255)/256), dim3(256), 0, stream, tab);
    hipLaunchKernelGGL(k_fill_all, dim3(116, 32), dim3(256), 0, stream, aout, out0);
    hipLaunchKernelGGL(k_proj, dim3(B_*S_/32, 2), dim3(256), 0, stream,
                       x, wqT, wkT, qb, kb);
    hipLaunchKernelGGL(k_score, dim3(512), dim3(256), 0, stream,
                       qb, kb, tab, aout);
}